// Round 1
// baseline (190.371 us; speedup 1.0000x reference)
//
#include <hip/hip_runtime.h>

// ROI max-pooling, faithful to the reference (including the buggy min/max
// ordering: when x1>x2 both collapse to original x2, then the +1 degenerate fix).
// feat: [B=4, C=64, H=128, W=128] f32; boxes: [B, N=64, 7] f32
// out:  [B, N, C, 7, 7] f32

constexpr int Bb = 4, Cc = 64, Hh = 128, Ww = 128, Nn = 64, BOX_DIM = 7;
constexpr int POOL = 7;
constexpr int CG = 16;   // channels per block

__global__ __launch_bounds__(256) void roi_pool_kernel(
    const float* __restrict__ feat,
    const float* __restrict__ boxes,
    float* __restrict__ out)
{
    const int bn = blockIdx.x;           // 0 .. B*N-1
    const int b  = bn / Nn;
    const int cg = blockIdx.y;           // channel group (CG channels each)

    // --- box decode (wave-uniform; scalar loads broadcast) ---
    const float* bx = boxes + (size_t)bn * BOX_DIM;
    bool valid = false;
#pragma unroll
    for (int i = 0; i < BOX_DIM; ++i) valid = valid || (bx[i] != 0.0f);

    float x1 = fminf(fmaxf(bx[0], 0.0f), (float)(Ww - 1));
    float y1 = fminf(fmaxf(bx[1], 0.0f), (float)(Hh - 1));
    float x2 = fminf(fmaxf(bx[2], 0.0f), (float)(Ww - 1));
    float y2 = fminf(fmaxf(bx[3], 0.0f), (float)(Hh - 1));
    // replicate reference ordering exactly (sequential updates)
    x1 = fminf(x1, x2);
    x2 = fmaxf(x1, x2);
    y1 = fminf(y1, y2);
    y2 = fmaxf(y1, y2);

    int x1i = (int)x1, x2i = (int)x2, y1i = (int)y1, y2i = (int)y2;
    if (x2i == x1i) x2i = x1i + 1;
    if (y2i == y1i) y2i = y1i + 1;
    const int Lh = y2i - y1i;
    const int Lw = x2i - x1i;

    const int c0 = cg * CG;

    // outputs for this block: CG channels x 49 bins
    for (int t = threadIdx.x; t < CG * POOL * POOL; t += 256) {
        const int c  = c0 + t / (POOL * POOL);
        const int pq = t % (POOL * POOL);
        const int p  = pq / POOL;
        const int q  = pq % POOL;

        const int ys = y1i + (p * Lh) / POOL;
        const int ye = y1i + ((p + 1) * Lh + POOL - 1) / POOL;
        const int xs = x1i + (q * Lw) / POOL;
        const int xe = x1i + ((q + 1) * Lw + POOL - 1) / POOL;

        const float* fp = feat + ((size_t)(b * Cc + c) * Hh) * Ww;
        float m = -INFINITY;
        for (int y = ys; y < ye; ++y) {
            const float* row = fp + (size_t)y * Ww;
            for (int x = xs; x < xe; ++x) {
                m = fmaxf(m, row[x]);
            }
        }
        if (!valid) m = 0.0f;
        out[((size_t)bn * Cc + c) * (POOL * POOL) + pq] = m;
    }
}

extern "C" void kernel_launch(void* const* d_in, const int* in_sizes, int n_in,
                              void* d_out, int out_size, void* d_ws, size_t ws_size,
                              hipStream_t stream) {
    const float* feat  = (const float*)d_in[0];
    const float* boxes = (const float*)d_in[1];
    float* out = (float*)d_out;

    dim3 grid(Bb * Nn, Cc / CG);   // 256 x 4 blocks
    roi_pool_kernel<<<grid, 256, 0, stream>>>(feat, boxes, out);
}

// Round 2
// 74.557 us; speedup vs baseline: 2.5533x; 2.5533x over previous
//
#include <hip/hip_runtime.h>

// ROI max-pooling, faithful to the reference (including the buggy min/max
// ordering). feat: [B=4, C=64, H=128, W=128] f32; boxes: [B, N=64, 7] f32
// out: [B, N, C, 7, 7] f32
//
// Round-1 restructure: one WAVE per (box, channel). Lanes cover the ROI width
// (coalesced loads); per-lane register column-max over each of the 7 y-bins;
// column maxes staged in LDS (padded pitch); 49 lanes reduce x-bins.

constexpr int Bb = 4, Cc = 64, Hh = 128, Ww = 128, Nn = 64, BOX_DIM = 7;
constexpr int POOL = 7;
constexpr int WAVES = 4;            // waves per block = channels per block
constexpr int PITCH = Ww + 1;       // 129 floats: breaks 32-bank power-of-2 stride

__global__ __launch_bounds__(256) void roi_pool_kernel(
    const float* __restrict__ feat,
    const float* __restrict__ boxes,
    float* __restrict__ out)
{
    __shared__ float colmax[WAVES][POOL][PITCH];   // 4*7*129*4 = 14448 B

    const int bn   = blockIdx.x;                   // 0 .. B*N-1
    const int b    = bn / Nn;
    const int wave = threadIdx.x >> 6;
    const int lane = threadIdx.x & 63;
    const int c    = blockIdx.y * WAVES + wave;    // channel for this wave

    // --- box decode (uniform across block) ---
    const float* bx = boxes + (size_t)bn * BOX_DIM;
    bool valid = false;
#pragma unroll
    for (int i = 0; i < BOX_DIM; ++i) valid = valid || (bx[i] != 0.0f);

    float x1 = fminf(fmaxf(bx[0], 0.0f), (float)(Ww - 1));
    float y1 = fminf(fmaxf(bx[1], 0.0f), (float)(Hh - 1));
    float x2 = fminf(fmaxf(bx[2], 0.0f), (float)(Ww - 1));
    float y2 = fminf(fmaxf(bx[3], 0.0f), (float)(Hh - 1));
    // reference ordering exactly (sequential updates)
    x1 = fminf(x1, x2);
    x2 = fmaxf(x1, x2);
    y1 = fminf(y1, y2);
    y2 = fmaxf(y1, y2);

    int x1i = (int)x1, x2i = (int)x2, y1i = (int)y1, y2i = (int)y2;
    if (x2i == x1i) x2i = x1i + 1;
    if (y2i == y1i) y2i = y1i + 1;
    const int Lh = y2i - y1i;      // >= 1
    const int Lw = x2i - x1i;      // >= 1, <= 127

    const float* fp = feat + ((size_t)(b * Cc + c) * Hh) * Ww;

    // --- stage 1: per-lane column maxes over each y-bin (coalesced in x) ---
#pragma unroll
    for (int chunk = 0; chunk < 2; ++chunk) {
        const int xoff = lane + chunk * 64;
        if (xoff < Lw) {
            const int x = x1i + xoff;
            float pm[POOL];
#pragma unroll
            for (int p = 0; p < POOL; ++p) pm[p] = -INFINITY;
#pragma unroll
            for (int p = 0; p < POOL; ++p) {
                const int ys = y1i + (p * Lh) / POOL;
                const int ye = y1i + ((p + 1) * Lh + POOL - 1) / POOL;
                for (int y = ys; y < ye; ++y)
                    pm[p] = fmaxf(pm[p], fp[(size_t)y * Ww + x]);
            }
#pragma unroll
            for (int p = 0; p < POOL; ++p) colmax[wave][p][xoff] = pm[p];
        }
    }

    __syncthreads();

    // --- stage 2: 49 lanes reduce x-bins from LDS, write 49 outputs ---
    if (lane < POOL * POOL) {
        const int p = lane / POOL;
        const int q = lane % POOL;
        const int xs = (q * Lw) / POOL;
        const int xe = ((q + 1) * Lw + POOL - 1) / POOL;
        float m = -INFINITY;
        for (int xo = xs; xo < xe; ++xo)
            m = fmaxf(m, colmax[wave][p][xo]);
        if (!valid) m = 0.0f;
        out[((size_t)bn * Cc + c) * (POOL * POOL) + lane] = m;
    }
}

extern "C" void kernel_launch(void* const* d_in, const int* in_sizes, int n_in,
                              void* d_out, int out_size, void* d_ws, size_t ws_size,
                              hipStream_t stream) {
    const float* feat  = (const float*)d_in[0];
    const float* boxes = (const float*)d_in[1];
    float* out = (float*)d_out;

    dim3 grid(Bb * Nn, Cc / WAVES);   // 256 x 16 = 4096 blocks, 4 waves each
    roi_pool_kernel<<<grid, 256, 0, stream>>>(feat, boxes, out);
}